// Round 2
// baseline (757.167 us; speedup 1.0000x reference)
//
#include <hip/hip_runtime.h>
#include <hip/hip_fp16.h>
#include <cstdint>
#include <cstddef>

#define NNODES 100000
#define NEDGES 1600000
#define NGRAPH 1024

// bucketized CSR build
#define BK 256                             // nodes per bucket (dst >> 8)
#define NBUCKET 391                        // ceil(NNODES / BK)
#define CHUNK 4096
#define NCHUNK 391                         // ceil(NEDGES / CHUNK)
#define NBE (NBUCKET * NCHUNK)             // 152881 count-matrix entries
#define SCAN_T 1024
#define PER_T ((NBE + SCAN_T - 1) / SCAN_T)  // 150

typedef __attribute__((ext_vector_type(8))) short short8;
typedef __attribute__((ext_vector_type(8))) unsigned short ushort8;
typedef __attribute__((ext_vector_type(4))) float f32x4;

__device__ inline float b2f(unsigned short u) {
  return __uint_as_float(((unsigned int)u) << 16);
}
__device__ inline unsigned short f2b(float f) {
  unsigned int x = __float_as_uint(f);
  x += 0x7fffu + ((x >> 16) & 1u);          // RNE
  return (unsigned short)(x >> 16);
}
// packed edge: (src << 15) | (fp16(weight) >> 1)   [weight >= 0 so sign bit = 0]
__device__ inline unsigned int pack_edge(int src, float w) {
  unsigned short hb = __half_as_ushort(__float2half_rn(w));
  return ((unsigned int)src << 15) | ((unsigned int)hb >> 1);
}
__device__ inline void unpack_edge(unsigned int p, int& src, float& w) {
  src = (int)(p >> 15);
  w = __half2float(__ushort_as_half((unsigned short)((p & 0x7fffu) << 1)));
}

// ---------------- weight prepack: W[HOUT][K] f32 -> bf16 MFMA-B order ----------------
__global__ __launch_bounds__(256) void prepack_kernel(
    const float* __restrict__ Wrel0, const float* __restrict__ Wroot0,
    const float* __restrict__ WrelR, const float* __restrict__ WrootR,
    const float* __restrict__ Wr1, unsigned short* __restrict__ dst)
{
  int g = blockIdx.x * 256 + threadIdx.x;
  if (g >= 15360) return;
  const float* src; int H, K, r; unsigned short* out;
  if (g < 1024)       { src = Wrel0;  H = 128; K = 64;  r = g;        out = dst + r * 8; }
  else if (g < 2048)  { src = Wroot0; H = 128; K = 64;  r = g - 1024; out = dst + 8192 + r * 8; }
  else if (g < 8192)  { int m = g - 2048; int l = m / 2048; r = m % 2048;
                        src = WrelR + l * 16384;  H = 128; K = 128;
                        out = dst + 16384 + l * 16384 + r * 8; }
  else if (g < 14336) { int m = g - 8192; int l = m / 2048; r = m % 2048;
                        src = WrootR + l * 16384; H = 128; K = 128;
                        out = dst + 65536 + l * 16384 + r * 8; }
  else                { src = Wr1;    H = 64;  K = 128; r = g - 14336; out = dst + 114688 + r * 8; }
  int n = r % H, k8 = r / H;
  const float* s = src + (size_t)n * K + k8 * 8;
#pragma unroll
  for (int j = 0; j < 8; j++) out[j] = f2b(s[j]);
}

// ---------------- x f32 -> bf16 ----------------
__global__ __launch_bounds__(256) void cvt_x_kernel(
    const float* __restrict__ x, unsigned short* __restrict__ xb)
{
  int i = blockIdx.x * 256 + threadIdx.x;
  if (i * 4 >= NNODES * 64) return;
  float4 v = *(const float4*)(x + i * 4);
  ushort4 o;
  o.x = f2b(v.x); o.y = f2b(v.y); o.z = f2b(v.z); o.w = f2b(v.w);
  *(ushort4*)(xb + i * 4) = o;
}

// ---------------- bucketized CSR build ----------------
// Pass 1: per-chunk histogram of dst buckets. cnt[b * NCHUNK + c] (bucket-major).
__global__ __launch_bounds__(256) void bucket_count_kernel(
    const int* __restrict__ ei, int* __restrict__ cnt)
{
  __shared__ int hist[NBUCKET];
  for (int i = threadIdx.x; i < NBUCKET; i += 256) hist[i] = 0;
  __syncthreads();
  int base = blockIdx.x * CHUNK;
  for (int t = threadIdx.x; t < CHUNK; t += 256) {
    int e = base + t;
    if (e < NEDGES) atomicAdd(&hist[ei[NEDGES + e] >> 8], 1);
  }
  __syncthreads();
  for (int i = threadIdx.x; i < NBUCKET; i += 256)
    cnt[i * NCHUNK + blockIdx.x] = hist[i];
}

// Pass 2: in-place exclusive scan of cnt (bucket-major order) -> segment bases.
__global__ __launch_bounds__(SCAN_T) void bucket_scan_kernel(int* __restrict__ cnt)
{
  __shared__ int s[SCAN_T];
  int t = threadIdx.x;
  int lo = t * PER_T, hi = lo + PER_T; if (hi > NBE) hi = NBE;
  int sum = 0;
  for (int i = lo; i < hi; i++) sum += cnt[i];
  s[t] = sum;
  __syncthreads();
#pragma unroll
  for (int off = 1; off < SCAN_T; off <<= 1) {
    int v = (t >= off) ? s[t - off] : 0;
    __syncthreads();
    s[t] += v;
    __syncthreads();
  }
  int run = s[t] - sum;
  for (int i = lo; i < hi; i++) { int v = cnt[i]; cnt[i] = run; run += v; }
}

// Pass 3: scatter edges into bucket-major record array (dst, packed_edge).
__global__ __launch_bounds__(256) void bucket_scatter_kernel(
    const int* __restrict__ ei, const float* __restrict__ ew,
    const int* __restrict__ basepos, uint2* __restrict__ rec)
{
  __shared__ int pos[NBUCKET];
  for (int i = threadIdx.x; i < NBUCKET; i += 256)
    pos[i] = basepos[i * NCHUNK + blockIdx.x];
  __syncthreads();
  int base = blockIdx.x * CHUNK;
  for (int t = threadIdx.x; t < CHUNK; t += 256) {
    int e = base + t;
    if (e < NEDGES) {
      int d = ei[NEDGES + e];
      int p = atomicAdd(&pos[d >> 8], 1);
      rec[p] = make_uint2((unsigned int)d, pack_edge(ei[e], ew[e]));
    }
  }
}

// Pass 4: one block per bucket. Local degree count + LDS scan writes row_ptr
// directly; then scatter epack into the bucket's contiguous 16KB window
// (L2-resident, lines completed within one block -> full-line writebacks).
__global__ __launch_bounds__(256) void bucket_fill_kernel(
    const int* __restrict__ basepos, const uint2* __restrict__ rec,
    unsigned int* __restrict__ epack, int* __restrict__ row_ptr)
{
  __shared__ int off[BK];
  __shared__ int s[256];
  int b = blockIdx.x, t = threadIdx.x;
  int start = basepos[b * NCHUNK];
  int end = (b + 1 < NBUCKET) ? basepos[(b + 1) * NCHUNK] : NEDGES;
  int nbase = b * BK;
  off[t] = 0;
  __syncthreads();
  for (int i = start + t; i < end; i += 256)
    atomicAdd(&off[rec[i].x - nbase], 1);
  __syncthreads();
  int v = off[t];
  s[t] = v;
  __syncthreads();
#pragma unroll
  for (int o = 1; o < 256; o <<= 1) {
    int u = (t >= o) ? s[t - o] : 0;
    __syncthreads();
    s[t] += u;
    __syncthreads();
  }
  int ex = s[t] - v;
  int g = nbase + t;
  if (g <= NNODES) row_ptr[g] = start + ex;   // g==NNODES -> start+ex == NEDGES
  __syncthreads();
  off[t] = ex;
  __syncthreads();
  for (int i = start + t; i < end; i += 256) {
    uint2 r = rec[i];
    int lp = atomicAdd(&off[r.x - nbase], 1);
    epack[start + lp] = r.y;
  }
}

// ---------------- graph pointer (batch sorted) ----------------
__global__ __launch_bounds__(256) void gptr_kernel(
    const int* __restrict__ batch, int* __restrict__ gptr)
{
  int i = blockIdx.x * 256 + threadIdx.x;
  if (i >= NNODES) return;
  int b = batch[i];
  int bn = (i + 1 < NNODES) ? batch[i + 1] : NGRAPH;
  for (int g = b + 1; g <= bn; g++) gptr[g] = i + 1;
  if (i == 0) for (int g = 0; g <= b; g++) gptr[g] = 0;
}

// ---------------- bf16 gather aggregation ----------------
// agg128: wave per node, quarter-split, 4-deep unroll -> 16 rows in flight/wave.
__global__ __launch_bounds__(256) void agg128_kernel(
    const int* __restrict__ row_ptr, const unsigned int* __restrict__ epack,
    const unsigned short* __restrict__ x, unsigned short* __restrict__ agg)
{
  int node = blockIdx.x * 4 + (threadIdx.x >> 6);
  int lane = threadIdx.x & 63;
  if (node >= NNODES) return;
  int q = lane >> 4, sl = lane & 15;
  int s = row_ptr[node], e = row_ptr[node + 1];
  float acc[8];
#pragma unroll
  for (int j = 0; j < 8; j++) acc[j] = 0.f;

  for (int i = s + q; i < e; i += 16) {
    unsigned int p0 = epack[i];
    unsigned int p1 = (i + 4  < e) ? epack[i + 4]  : 0u;
    unsigned int p2 = (i + 8  < e) ? epack[i + 8]  : 0u;
    unsigned int p3 = (i + 12 < e) ? epack[i + 12] : 0u;
    int s0, s1, s2, s3; float w0, w1, w2, w3;
    unpack_edge(p0, s0, w0);
    unpack_edge(p1, s1, w1);
    unpack_edge(p2, s2, w2);
    unpack_edge(p3, s3, w3);
    ushort8 r0 = *(const ushort8*)(x + (size_t)s0 * 128 + sl * 8);
    ushort8 r1 = *(const ushort8*)(x + (size_t)s1 * 128 + sl * 8);
    ushort8 r2 = *(const ushort8*)(x + (size_t)s2 * 128 + sl * 8);
    ushort8 r3 = *(const ushort8*)(x + (size_t)s3 * 128 + sl * 8);
#pragma unroll
    for (int j = 0; j < 8; j++)
      acc[j] += w0 * b2f(r0[j]) + w1 * b2f(r1[j]) +
                w2 * b2f(r2[j]) + w3 * b2f(r3[j]);
  }
#pragma unroll
  for (int j = 0; j < 8; j++) {
    acc[j] += __shfl_xor(acc[j], 16, 64);
    acc[j] += __shfl_xor(acc[j], 32, 64);
  }
  if (q == 0) {
    ushort8 o;
#pragma unroll
    for (int j = 0; j < 8; j++) o[j] = f2b(acc[j]);
    *(ushort8*)(agg + (size_t)node * 128 + sl * 8) = o;
  }
}

// agg64: wave per node, eighth-split, 2-deep unroll -> 16 rows in flight/wave.
__global__ __launch_bounds__(256) void agg64_kernel(
    const int* __restrict__ row_ptr, const unsigned int* __restrict__ epack,
    const unsigned short* __restrict__ x, unsigned short* __restrict__ agg)
{
  int node = blockIdx.x * 4 + (threadIdx.x >> 6);
  int lane = threadIdx.x & 63;
  if (node >= NNODES) return;
  int q = lane >> 3, sl = lane & 7;
  int s = row_ptr[node], e = row_ptr[node + 1];
  float acc[8];
#pragma unroll
  for (int j = 0; j < 8; j++) acc[j] = 0.f;

  for (int i = s + q; i < e; i += 16) {
    unsigned int p0 = epack[i];
    unsigned int p1 = (i + 8 < e) ? epack[i + 8] : 0u;
    int s0, s1; float w0, w1;
    unpack_edge(p0, s0, w0);
    unpack_edge(p1, s1, w1);
    ushort8 r0 = *(const ushort8*)(x + (size_t)s0 * 64 + sl * 8);
    ushort8 r1 = *(const ushort8*)(x + (size_t)s1 * 64 + sl * 8);
#pragma unroll
    for (int j = 0; j < 8; j++)
      acc[j] += w0 * b2f(r0[j]) + w1 * b2f(r1[j]);
  }
#pragma unroll
  for (int j = 0; j < 8; j++) {
    acc[j] += __shfl_xor(acc[j], 8, 64);
    acc[j] += __shfl_xor(acc[j], 16, 64);
    acc[j] += __shfl_xor(acc[j], 32, 64);
  }
  if (q == 0) {
    ushort8 o;
#pragma unroll
    for (int j = 0; j < 8; j++) o[j] = f2b(acc[j]);
    *(ushort8*)(agg + (size_t)node * 64 + sl * 8) = o;
  }
}

// ---------------- LDS-free MFMA bf16 GEMM ----------------
template <int KDIM, int HOUT, int MT, bool DUAL, bool RELU>
__global__ __launch_bounds__(256) void mfma_gemm(
    const unsigned short* __restrict__ A1, const unsigned short* __restrict__ W1,
    const unsigned short* __restrict__ A2, const unsigned short* __restrict__ W2,
    const float* __restrict__ bias, unsigned short* __restrict__ out)
{
  constexpr int NT2 = HOUT / 16;
  constexpr int KC = KDIM / 32;
  const int wave = threadIdx.x >> 6, lane = threadIdx.x & 63;
  const int quad = lane >> 4, l16 = lane & 15;
  const int n0 = (blockIdx.x * 4 + wave) * (MT * 16);

  f32x4 acc[MT][NT2];
#pragma unroll
  for (int m = 0; m < MT; m++)
#pragma unroll
    for (int t = 0; t < NT2; t++) acc[m][t] = (f32x4){0.f, 0.f, 0.f, 0.f};

  int nodes[MT];
#pragma unroll
  for (int m = 0; m < MT; m++) {
    int nd = n0 + m * 16 + l16;
    nodes[m] = nd < NNODES ? nd : NNODES - 1;
  }

#pragma unroll
  for (int c = 0; c < KC; c++) {
    short8 bfr[NT2];
#pragma unroll
    for (int t = 0; t < NT2; t++)
      bfr[t] = *(const short8*)(W1 + ((size_t)(c * 4 + quad) * HOUT + t * 16 + l16) * 8);
#pragma unroll
    for (int m = 0; m < MT; m++) {
      short8 af = *(const short8*)(A1 + (size_t)nodes[m] * KDIM + c * 32 + quad * 8);
#pragma unroll
      for (int t = 0; t < NT2; t++)
        acc[m][t] = __builtin_amdgcn_mfma_f32_16x16x32_bf16(af, bfr[t], acc[m][t], 0, 0, 0);
    }
    if (DUAL) {
#pragma unroll
      for (int t = 0; t < NT2; t++)
        bfr[t] = *(const short8*)(W2 + ((size_t)(c * 4 + quad) * HOUT + t * 16 + l16) * 8);
#pragma unroll
      for (int m = 0; m < MT; m++) {
        short8 af = *(const short8*)(A2 + (size_t)nodes[m] * KDIM + c * 32 + quad * 8);
#pragma unroll
        for (int t = 0; t < NT2; t++)
          acc[m][t] = __builtin_amdgcn_mfma_f32_16x16x32_bf16(af, bfr[t], acc[m][t], 0, 0, 0);
      }
    }
  }

#pragma unroll
  for (int m = 0; m < MT; m++) {
    int rowbase = n0 + m * 16 + quad * 4;
#pragma unroll
    for (int t = 0; t < NT2; t++) {
      float b = bias[t * 16 + l16];
#pragma unroll
      for (int r = 0; r < 4; r++) {
        int nd = rowbase + r;
        if (nd < NNODES) {
          float v = acc[m][t][r] + b;
          if (RELU) v = fmaxf(v, 0.f);
          out[(size_t)nd * HOUT + t * 16 + l16] = f2b(v);
        }
      }
    }
  }
}

// ---------------- readout: per-graph block reduction ----------------
__global__ __launch_bounds__(256) void readout_reduce_kernel(
    const unsigned short* __restrict__ h, const float* __restrict__ Wr2,
    const float* __restrict__ br2, const int* __restrict__ gptr,
    float* __restrict__ out)
{
  __shared__ float wsum[4];
  int g = blockIdx.x;
  int s = gptr[g], e = gptr[g + 1];
  int wave = threadIdx.x >> 6, lane = threadIdx.x & 63;
  float w2 = Wr2[lane];
  float acc = 0.f;
  for (int n = s + wave; n < e; n += 4)
    acc += b2f(h[(size_t)n * 64 + lane]) * w2;
#pragma unroll
  for (int off = 32; off >= 1; off >>= 1) acc += __shfl_xor(acc, off, 64);
  if (lane == 0) wsum[wave] = acc;
  __syncthreads();
  if (threadIdx.x == 0) {
    float cnt = (float)(e - s);
    float sum = wsum[0] + wsum[1] + wsum[2] + wsum[3] + cnt * br2[0];
    out[g] = sum / fmaxf(cnt, 1.f);
  }
}

// ---------------- launch ----------------
extern "C" void kernel_launch(void* const* d_in, const int* in_sizes, int n_in,
                              void* d_out, int out_size, void* d_ws, size_t ws_size,
                              hipStream_t stream)
{
  const float* x      = (const float*)d_in[0];
  const int*   ei     = (const int*)d_in[1];
  const float* ew     = (const float*)d_in[2];
  const int*   batch  = (const int*)d_in[3];
  const float* Wroot0 = (const float*)d_in[4];
  const float* Wrel0  = (const float*)d_in[5];
  const float* b0     = (const float*)d_in[6];
  const float* WrootR = (const float*)d_in[7];
  const float* WrelR  = (const float*)d_in[8];
  const float* bR     = (const float*)d_in[9];
  const float* Wr1    = (const float*)d_in[10];
  const float* br1    = (const float*)d_in[11];
  const float* Wr2    = (const float*)d_in[12];
  const float* br2    = (const float*)d_in[13];

  char* ws = (char*)d_ws;
  unsigned short* wp   = (unsigned short*)ws;                 // 122880 bf16, pad to 131072
  unsigned short* xb   = wp + 131072;                         // N*64 bf16
  unsigned short* agg0 = xb + (size_t)NNODES * 64;            // N*64 bf16
  unsigned short* bufA = agg0 + (size_t)NNODES * 64;          // N*128 bf16
  unsigned short* bufB = bufA + (size_t)NNODES * 128;         // N*128 bf16
  unsigned short* hbuf = bufB + (size_t)NNODES * 128;         // N*64 bf16
  int*  cnt      = (int*)(hbuf + (size_t)NNODES * 64);        // NBE ints (~600KB)
  int*  row_ptr  = cnt + ((NBE + 63) & ~63);
  int*  gptr     = row_ptr + NNODES + 2;
  unsigned int* epack = (unsigned int*)(gptr + NGRAPH + 2);   // E uint = 6.4MB
  // rec aliases bufA (12.8MB <= 25.6MB); bufA first written by layer-1 agg128,
  // long after bucket_fill_kernel has consumed rec.
  uint2* rec = (uint2*)bufA;

  prepack_kernel<<<60, 256, 0, stream>>>(Wrel0, Wroot0, WrelR, WrootR, Wr1, wp);
  cvt_x_kernel<<<(NNODES * 64 / 4 + 255) / 256, 256, 0, stream>>>(x, xb);

  const unsigned short* pWrel0  = wp;
  const unsigned short* pWroot0 = wp + 8192;
  const unsigned short* pWrelR  = wp + 16384;
  const unsigned short* pWrootR = wp + 65536;
  const unsigned short* pWr1    = wp + 114688;

  // bucketized CSR build (by dst) + graph ptr
  bucket_count_kernel<<<NCHUNK, 256, 0, stream>>>(ei, cnt);
  bucket_scan_kernel<<<1, SCAN_T, 0, stream>>>(cnt);
  bucket_scatter_kernel<<<NCHUNK, 256, 0, stream>>>(ei, ew, cnt, rec);
  bucket_fill_kernel<<<NBUCKET, 256, 0, stream>>>(cnt, rec, epack, row_ptr);
  gptr_kernel<<<(NNODES + 255) / 256, 256, 0, stream>>>(batch, gptr);

  // layer 0: 64 -> 128
  agg64_kernel<<<(NNODES + 3) / 4, 256, 0, stream>>>(row_ptr, epack, xb, agg0);
  mfma_gemm<64, 128, 2, true, false><<<(NNODES + 127) / 128, 256, 0, stream>>>(
      agg0, pWrel0, xb, pWroot0, b0, bufB);

  // layers 1..3: 128 -> 128
  unsigned short* bufs[2] = { bufB, bufA };
  for (int l = 0; l < 3; l++) {
    unsigned short* in  = bufs[l & 1];
    unsigned short* agg = bufs[(l & 1) ^ 1];
    agg128_kernel<<<(NNODES + 3) / 4, 256, 0, stream>>>(row_ptr, epack, in, agg);
    mfma_gemm<128, 128, 2, true, false><<<(NNODES + 127) / 128, 256, 0, stream>>>(
        agg, pWrelR + l * 16384, in, pWrootR + l * 16384, bR + l * 128, agg);
  }
  // y3 in bufA

  // readout
  mfma_gemm<128, 64, 4, false, true><<<(NNODES + 255) / 256, 256, 0, stream>>>(
      bufA, pWr1, nullptr, nullptr, br1, hbuf);
  readout_reduce_kernel<<<NGRAPH, 256, 0, stream>>>(hbuf, Wr2, br2, gptr, (float*)d_out);
}

// Round 3
// 506.054 us; speedup vs baseline: 1.4962x; 1.4962x over previous
//
#include <hip/hip_runtime.h>
#include <hip/hip_fp16.h>
#include <cstdint>
#include <cstddef>

#define NNODES 100000
#define NEDGES 1600000
#define NGRAPH 1024

// bucketized CSR build
#define BK 256                             // nodes per bucket (dst >> 8)
#define NBUCKET 391                        // ceil(NNODES / BK)
#define CHUNK 4096
#define NCHUNK 391                         // ceil(NEDGES / CHUNK)
#define NBE (NBUCKET * NCHUNK)             // 152881 count-matrix entries

typedef __attribute__((ext_vector_type(8))) short short8;
typedef __attribute__((ext_vector_type(8))) unsigned short ushort8;
typedef __attribute__((ext_vector_type(4))) float f32x4;

__device__ inline float b2f(unsigned short u) {
  return __uint_as_float(((unsigned int)u) << 16);
}
__device__ inline unsigned short f2b(float f) {
  unsigned int x = __float_as_uint(f);
  x += 0x7fffu + ((x >> 16) & 1u);          // RNE
  return (unsigned short)(x >> 16);
}
// packed edge: (src << 15) | (fp16(weight) >> 1)   [weight >= 0 so sign bit = 0]
__device__ inline unsigned int pack_edge(int src, float w) {
  unsigned short hb = __half_as_ushort(__float2half_rn(w));
  return ((unsigned int)src << 15) | ((unsigned int)hb >> 1);
}
__device__ inline void unpack_edge(unsigned int p, int& src, float& w) {
  src = (int)(p >> 15);
  w = __half2float(__ushort_as_half((unsigned short)((p & 0x7fffu) << 1)));
}

// ---------------- weight prepack: W[HOUT][K] f32 -> bf16 MFMA-B order ----------------
__global__ __launch_bounds__(256) void prepack_kernel(
    const float* __restrict__ Wrel0, const float* __restrict__ Wroot0,
    const float* __restrict__ WrelR, const float* __restrict__ WrootR,
    const float* __restrict__ Wr1, unsigned short* __restrict__ dst)
{
  int g = blockIdx.x * 256 + threadIdx.x;
  if (g >= 15360) return;
  const float* src; int H, K, r; unsigned short* out;
  if (g < 1024)       { src = Wrel0;  H = 128; K = 64;  r = g;        out = dst + r * 8; }
  else if (g < 2048)  { src = Wroot0; H = 128; K = 64;  r = g - 1024; out = dst + 8192 + r * 8; }
  else if (g < 8192)  { int m = g - 2048; int l = m / 2048; r = m % 2048;
                        src = WrelR + l * 16384;  H = 128; K = 128;
                        out = dst + 16384 + l * 16384 + r * 8; }
  else if (g < 14336) { int m = g - 8192; int l = m / 2048; r = m % 2048;
                        src = WrootR + l * 16384; H = 128; K = 128;
                        out = dst + 65536 + l * 16384 + r * 8; }
  else                { src = Wr1;    H = 64;  K = 128; r = g - 14336; out = dst + 114688 + r * 8; }
  int n = r % H, k8 = r / H;
  const float* s = src + (size_t)n * K + k8 * 8;
#pragma unroll
  for (int j = 0; j < 8; j++) out[j] = f2b(s[j]);
}

// ---------------- x f32 -> bf16 ----------------
__global__ __launch_bounds__(256) void cvt_x_kernel(
    const float* __restrict__ x, unsigned short* __restrict__ xb)
{
  int i = blockIdx.x * 256 + threadIdx.x;
  if (i * 4 >= NNODES * 64) return;
  float4 v = *(const float4*)(x + i * 4);
  ushort4 o;
  o.x = f2b(v.x); o.y = f2b(v.y); o.z = f2b(v.z); o.w = f2b(v.w);
  *(ushort4*)(xb + i * 4) = o;
}

// ---------------- bucketized CSR build ----------------
// Pass 1: per-chunk histogram of dst buckets. cnt[b * NCHUNK + c] (bucket-major).
__global__ __launch_bounds__(256) void bucket_count_kernel(
    const int* __restrict__ ei, int* __restrict__ cnt)
{
  __shared__ int hist[NBUCKET];
  for (int i = threadIdx.x; i < NBUCKET; i += 256) hist[i] = 0;
  __syncthreads();
  int base = blockIdx.x * CHUNK;
  for (int t = threadIdx.x; t < CHUNK; t += 256) {
    int e = base + t;
    if (e < NEDGES) atomicAdd(&hist[ei[NEDGES + e] >> 8], 1);
  }
  __syncthreads();
  for (int i = threadIdx.x; i < NBUCKET; i += 256)
    cnt[i * NCHUNK + blockIdx.x] = hist[i];
}

// Pass 2a: per-bucket-row exclusive scan (in-row offsets) + row total.
__global__ __launch_bounds__(512) void row_scan_kernel(
    int* __restrict__ cnt, int* __restrict__ rowsum)
{
  __shared__ int s[512];
  int b = blockIdx.x, t = threadIdx.x;
  int v = (t < NCHUNK) ? cnt[b * NCHUNK + t] : 0;
  s[t] = v;
  __syncthreads();
#pragma unroll
  for (int off = 1; off < 512; off <<= 1) {
    int u = (t >= off) ? s[t - off] : 0;
    __syncthreads();
    s[t] += u;
    __syncthreads();
  }
  if (t < NCHUNK) cnt[b * NCHUNK + t] = s[t] - v;
  if (t == 511) rowsum[b] = s[511];
}

// Pass 2b: exclusive scan of the 391 row totals -> rowbase[NBUCKET+1].
__global__ __launch_bounds__(512) void rowbase_scan_kernel(
    const int* __restrict__ rowsum, int* __restrict__ rowbase)
{
  __shared__ int s[512];
  int t = threadIdx.x;
  int v = (t < NBUCKET) ? rowsum[t] : 0;
  s[t] = v;
  __syncthreads();
#pragma unroll
  for (int off = 1; off < 512; off <<= 1) {
    int u = (t >= off) ? s[t - off] : 0;
    __syncthreads();
    s[t] += u;
    __syncthreads();
  }
  if (t < NBUCKET) rowbase[t] = s[t] - v;
  if (t == 511) rowbase[NBUCKET] = s[511];   // == NEDGES
}

// Pass 3: scatter edges into bucket-major record array (dst, packed_edge).
// Absolute position = rowbase[bucket] + in-row offset for (bucket, chunk).
__global__ __launch_bounds__(256) void bucket_scatter_kernel(
    const int* __restrict__ ei, const float* __restrict__ ew,
    const int* __restrict__ cnt, const int* __restrict__ rowbase,
    uint2* __restrict__ rec)
{
  __shared__ int pos[NBUCKET];
  for (int i = threadIdx.x; i < NBUCKET; i += 256)
    pos[i] = rowbase[i] + cnt[i * NCHUNK + blockIdx.x];
  __syncthreads();
  int base = blockIdx.x * CHUNK;
  for (int t = threadIdx.x; t < CHUNK; t += 256) {
    int e = base + t;
    if (e < NEDGES) {
      int d = ei[NEDGES + e];
      int p = atomicAdd(&pos[d >> 8], 1);
      rec[p] = make_uint2((unsigned int)d, pack_edge(ei[e], ew[e]));
    }
  }
}

// Pass 4: one block per bucket. Local degree count + LDS scan writes row_ptr
// directly; then scatter epack into the bucket's contiguous 16KB window
// (L2-resident, lines completed within one block -> full-line writebacks).
__global__ __launch_bounds__(256) void bucket_fill_kernel(
    const int* __restrict__ rowbase, const uint2* __restrict__ rec,
    unsigned int* __restrict__ epack, int* __restrict__ row_ptr)
{
  __shared__ int off[BK];
  __shared__ int s[256];
  int b = blockIdx.x, t = threadIdx.x;
  int start = rowbase[b];
  int end = rowbase[b + 1];
  int nbase = b * BK;
  off[t] = 0;
  __syncthreads();
  for (int i = start + t; i < end; i += 256)
    atomicAdd(&off[rec[i].x - nbase], 1);
  __syncthreads();
  int v = off[t];
  s[t] = v;
  __syncthreads();
#pragma unroll
  for (int o = 1; o < 256; o <<= 1) {
    int u = (t >= o) ? s[t - o] : 0;
    __syncthreads();
    s[t] += u;
    __syncthreads();
  }
  int ex = s[t] - v;
  int g = nbase + t;
  if (g <= NNODES) row_ptr[g] = start + ex;   // g==NNODES -> start+ex == NEDGES
  __syncthreads();
  off[t] = ex;
  __syncthreads();
  for (int i = start + t; i < end; i += 256) {
    uint2 r = rec[i];
    int lp = atomicAdd(&off[r.x - nbase], 1);
    epack[start + lp] = r.y;
  }
}

// ---------------- graph pointer (batch sorted) ----------------
__global__ __launch_bounds__(256) void gptr_kernel(
    const int* __restrict__ batch, int* __restrict__ gptr)
{
  int i = blockIdx.x * 256 + threadIdx.x;
  if (i >= NNODES) return;
  int b = batch[i];
  int bn = (i + 1 < NNODES) ? batch[i + 1] : NGRAPH;
  for (int g = b + 1; g <= bn; g++) gptr[g] = i + 1;
  if (i == 0) for (int g = 0; g <= b; g++) gptr[g] = 0;
}

// ---------------- bf16 gather aggregation ----------------
// agg128: wave per node, quarter-split, 4-deep unroll -> 16 rows in flight/wave.
__global__ __launch_bounds__(256) void agg128_kernel(
    const int* __restrict__ row_ptr, const unsigned int* __restrict__ epack,
    const unsigned short* __restrict__ x, unsigned short* __restrict__ agg)
{
  int node = blockIdx.x * 4 + (threadIdx.x >> 6);
  int lane = threadIdx.x & 63;
  if (node >= NNODES) return;
  int q = lane >> 4, sl = lane & 15;
  int s = row_ptr[node], e = row_ptr[node + 1];
  float acc[8];
#pragma unroll
  for (int j = 0; j < 8; j++) acc[j] = 0.f;

  for (int i = s + q; i < e; i += 16) {
    unsigned int p0 = epack[i];
    unsigned int p1 = (i + 4  < e) ? epack[i + 4]  : 0u;
    unsigned int p2 = (i + 8  < e) ? epack[i + 8]  : 0u;
    unsigned int p3 = (i + 12 < e) ? epack[i + 12] : 0u;
    int s0, s1, s2, s3; float w0, w1, w2, w3;
    unpack_edge(p0, s0, w0);
    unpack_edge(p1, s1, w1);
    unpack_edge(p2, s2, w2);
    unpack_edge(p3, s3, w3);
    ushort8 r0 = *(const ushort8*)(x + (size_t)s0 * 128 + sl * 8);
    ushort8 r1 = *(const ushort8*)(x + (size_t)s1 * 128 + sl * 8);
    ushort8 r2 = *(const ushort8*)(x + (size_t)s2 * 128 + sl * 8);
    ushort8 r3 = *(const ushort8*)(x + (size_t)s3 * 128 + sl * 8);
#pragma unroll
    for (int j = 0; j < 8; j++)
      acc[j] += w0 * b2f(r0[j]) + w1 * b2f(r1[j]) +
                w2 * b2f(r2[j]) + w3 * b2f(r3[j]);
  }
#pragma unroll
  for (int j = 0; j < 8; j++) {
    acc[j] += __shfl_xor(acc[j], 16, 64);
    acc[j] += __shfl_xor(acc[j], 32, 64);
  }
  if (q == 0) {
    ushort8 o;
#pragma unroll
    for (int j = 0; j < 8; j++) o[j] = f2b(acc[j]);
    *(ushort8*)(agg + (size_t)node * 128 + sl * 8) = o;
  }
}

// agg64: wave per node, eighth-split, 2-deep unroll -> 16 rows in flight/wave.
__global__ __launch_bounds__(256) void agg64_kernel(
    const int* __restrict__ row_ptr, const unsigned int* __restrict__ epack,
    const unsigned short* __restrict__ x, unsigned short* __restrict__ agg)
{
  int node = blockIdx.x * 4 + (threadIdx.x >> 6);
  int lane = threadIdx.x & 63;
  if (node >= NNODES) return;
  int q = lane >> 3, sl = lane & 7;
  int s = row_ptr[node], e = row_ptr[node + 1];
  float acc[8];
#pragma unroll
  for (int j = 0; j < 8; j++) acc[j] = 0.f;

  for (int i = s + q; i < e; i += 16) {
    unsigned int p0 = epack[i];
    unsigned int p1 = (i + 8 < e) ? epack[i + 8] : 0u;
    int s0, s1; float w0, w1;
    unpack_edge(p0, s0, w0);
    unpack_edge(p1, s1, w1);
    ushort8 r0 = *(const ushort8*)(x + (size_t)s0 * 64 + sl * 8);
    ushort8 r1 = *(const ushort8*)(x + (size_t)s1 * 64 + sl * 8);
#pragma unroll
    for (int j = 0; j < 8; j++)
      acc[j] += w0 * b2f(r0[j]) + w1 * b2f(r1[j]);
  }
#pragma unroll
  for (int j = 0; j < 8; j++) {
    acc[j] += __shfl_xor(acc[j], 8, 64);
    acc[j] += __shfl_xor(acc[j], 16, 64);
    acc[j] += __shfl_xor(acc[j], 32, 64);
  }
  if (q == 0) {
    ushort8 o;
#pragma unroll
    for (int j = 0; j < 8; j++) o[j] = f2b(acc[j]);
    *(ushort8*)(agg + (size_t)node * 64 + sl * 8) = o;
  }
}

// ---------------- LDS-free MFMA bf16 GEMM ----------------
template <int KDIM, int HOUT, int MT, bool DUAL, bool RELU>
__global__ __launch_bounds__(256) void mfma_gemm(
    const unsigned short* __restrict__ A1, const unsigned short* __restrict__ W1,
    const unsigned short* __restrict__ A2, const unsigned short* __restrict__ W2,
    const float* __restrict__ bias, unsigned short* __restrict__ out)
{
  constexpr int NT2 = HOUT / 16;
  constexpr int KC = KDIM / 32;
  const int wave = threadIdx.x >> 6, lane = threadIdx.x & 63;
  const int quad = lane >> 4, l16 = lane & 15;
  const int n0 = (blockIdx.x * 4 + wave) * (MT * 16);

  f32x4 acc[MT][NT2];
#pragma unroll
  for (int m = 0; m < MT; m++)
#pragma unroll
    for (int t = 0; t < NT2; t++) acc[m][t] = (f32x4){0.f, 0.f, 0.f, 0.f};

  int nodes[MT];
#pragma unroll
  for (int m = 0; m < MT; m++) {
    int nd = n0 + m * 16 + l16;
    nodes[m] = nd < NNODES ? nd : NNODES - 1;
  }

#pragma unroll
  for (int c = 0; c < KC; c++) {
    short8 bfr[NT2];
#pragma unroll
    for (int t = 0; t < NT2; t++)
      bfr[t] = *(const short8*)(W1 + ((size_t)(c * 4 + quad) * HOUT + t * 16 + l16) * 8);
#pragma unroll
    for (int m = 0; m < MT; m++) {
      short8 af = *(const short8*)(A1 + (size_t)nodes[m] * KDIM + c * 32 + quad * 8);
#pragma unroll
      for (int t = 0; t < NT2; t++)
        acc[m][t] = __builtin_amdgcn_mfma_f32_16x16x32_bf16(af, bfr[t], acc[m][t], 0, 0, 0);
    }
    if (DUAL) {
#pragma unroll
      for (int t = 0; t < NT2; t++)
        bfr[t] = *(const short8*)(W2 + ((size_t)(c * 4 + quad) * HOUT + t * 16 + l16) * 8);
#pragma unroll
      for (int m = 0; m < MT; m++) {
        short8 af = *(const short8*)(A2 + (size_t)nodes[m] * KDIM + c * 32 + quad * 8);
#pragma unroll
        for (int t = 0; t < NT2; t++)
          acc[m][t] = __builtin_amdgcn_mfma_f32_16x16x32_bf16(af, bfr[t], acc[m][t], 0, 0, 0);
      }
    }
  }

#pragma unroll
  for (int m = 0; m < MT; m++) {
    int rowbase = n0 + m * 16 + quad * 4;
#pragma unroll
    for (int t = 0; t < NT2; t++) {
      float b = bias[t * 16 + l16];
#pragma unroll
      for (int r = 0; r < 4; r++) {
        int nd = rowbase + r;
        if (nd < NNODES) {
          float v = acc[m][t][r] + b;
          if (RELU) v = fmaxf(v, 0.f);
          out[(size_t)nd * HOUT + t * 16 + l16] = f2b(v);
        }
      }
    }
  }
}

// ---------------- readout: per-graph block reduction ----------------
__global__ __launch_bounds__(256) void readout_reduce_kernel(
    const unsigned short* __restrict__ h, const float* __restrict__ Wr2,
    const float* __restrict__ br2, const int* __restrict__ gptr,
    float* __restrict__ out)
{
  __shared__ float wsum[4];
  int g = blockIdx.x;
  int s = gptr[g], e = gptr[g + 1];
  int wave = threadIdx.x >> 6, lane = threadIdx.x & 63;
  float w2 = Wr2[lane];
  float acc = 0.f;
  for (int n = s + wave; n < e; n += 4)
    acc += b2f(h[(size_t)n * 64 + lane]) * w2;
#pragma unroll
  for (int off = 32; off >= 1; off >>= 1) acc += __shfl_xor(acc, off, 64);
  if (lane == 0) wsum[wave] = acc;
  __syncthreads();
  if (threadIdx.x == 0) {
    float cnt = (float)(e - s);
    float sum = wsum[0] + wsum[1] + wsum[2] + wsum[3] + cnt * br2[0];
    out[g] = sum / fmaxf(cnt, 1.f);
  }
}

// ---------------- launch ----------------
extern "C" void kernel_launch(void* const* d_in, const int* in_sizes, int n_in,
                              void* d_out, int out_size, void* d_ws, size_t ws_size,
                              hipStream_t stream)
{
  const float* x      = (const float*)d_in[0];
  const int*   ei     = (const int*)d_in[1];
  const float* ew     = (const float*)d_in[2];
  const int*   batch  = (const int*)d_in[3];
  const float* Wroot0 = (const float*)d_in[4];
  const float* Wrel0  = (const float*)d_in[5];
  const float* b0     = (const float*)d_in[6];
  const float* WrootR = (const float*)d_in[7];
  const float* WrelR  = (const float*)d_in[8];
  const float* bR     = (const float*)d_in[9];
  const float* Wr1    = (const float*)d_in[10];
  const float* br1    = (const float*)d_in[11];
  const float* Wr2    = (const float*)d_in[12];
  const float* br2    = (const float*)d_in[13];

  char* ws = (char*)d_ws;
  unsigned short* wp   = (unsigned short*)ws;                 // 122880 bf16, pad to 131072
  unsigned short* xb   = wp + 131072;                         // N*64 bf16
  unsigned short* agg0 = xb + (size_t)NNODES * 64;            // N*64 bf16
  unsigned short* bufA = agg0 + (size_t)NNODES * 64;          // N*128 bf16
  unsigned short* bufB = bufA + (size_t)NNODES * 128;         // N*128 bf16
  unsigned short* hbuf = bufB + (size_t)NNODES * 128;         // N*64 bf16
  int*  cnt      = (int*)(hbuf + (size_t)NNODES * 64);        // NBE ints (~600KB)
  int*  rowsum   = cnt + ((NBE + 63) & ~63);
  int*  rowbase  = rowsum + NBUCKET + 1;
  int*  row_ptr  = rowbase + NBUCKET + 1;
  int*  gptr     = row_ptr + NNODES + 2;
  unsigned int* epack = (unsigned int*)(gptr + NGRAPH + 2);   // E uint = 6.4MB
  // rec aliases bufA (12.8MB <= 25.6MB); bufA first written by layer-1 agg128,
  // long after bucket_fill_kernel has consumed rec.
  uint2* rec = (uint2*)bufA;

  prepack_kernel<<<60, 256, 0, stream>>>(Wrel0, Wroot0, WrelR, WrootR, Wr1, wp);
  cvt_x_kernel<<<(NNODES * 64 / 4 + 255) / 256, 256, 0, stream>>>(x, xb);

  const unsigned short* pWrel0  = wp;
  const unsigned short* pWroot0 = wp + 8192;
  const unsigned short* pWrelR  = wp + 16384;
  const unsigned short* pWrootR = wp + 65536;
  const unsigned short* pWr1    = wp + 114688;

  // bucketized CSR build (by dst) + graph ptr
  bucket_count_kernel<<<NCHUNK, 256, 0, stream>>>(ei, cnt);
  row_scan_kernel<<<NBUCKET, 512, 0, stream>>>(cnt, rowsum);
  rowbase_scan_kernel<<<1, 512, 0, stream>>>(rowsum, rowbase);
  bucket_scatter_kernel<<<NCHUNK, 256, 0, stream>>>(ei, ew, cnt, rowbase, rec);
  bucket_fill_kernel<<<NBUCKET, 256, 0, stream>>>(rowbase, rec, epack, row_ptr);
  gptr_kernel<<<(NNODES + 255) / 256, 256, 0, stream>>>(batch, gptr);

  // layer 0: 64 -> 128
  agg64_kernel<<<(NNODES + 3) / 4, 256, 0, stream>>>(row_ptr, epack, xb, agg0);
  mfma_gemm<64, 128, 2, true, false><<<(NNODES + 127) / 128, 256, 0, stream>>>(
      agg0, pWrel0, xb, pWroot0, b0, bufB);

  // layers 1..3: 128 -> 128
  unsigned short* bufs[2] = { bufB, bufA };
  for (int l = 0; l < 3; l++) {
    unsigned short* in  = bufs[l & 1];
    unsigned short* agg = bufs[(l & 1) ^ 1];
    agg128_kernel<<<(NNODES + 3) / 4, 256, 0, stream>>>(row_ptr, epack, in, agg);
    mfma_gemm<128, 128, 2, true, false><<<(NNODES + 127) / 128, 256, 0, stream>>>(
        agg, pWrelR + l * 16384, in, pWrootR + l * 16384, bR + l * 128, agg);
  }
  // y3 in bufA

  // readout
  mfma_gemm<128, 64, 4, false, true><<<(NNODES + 255) / 256, 256, 0, stream>>>(
      bufA, pWr1, nullptr, nullptr, br1, hbuf);
  readout_reduce_kernel<<<NGRAPH, 256, 0, stream>>>(hbuf, Wr2, br2, gptr, (float*)d_out);
}